// Round 6
// baseline (15996.510 us; speedup 1.0000x reference)
//
#include <hip/hip_runtime.h>

#define BB 32
#define TSRC 12
#define HORZ 12
#define NN 883
#define DD 10
#define HH 64
#define BN (BB*NN)     // 28256
#define BNP 28288      // 64-aligned stride

static __device__ __forceinline__ float sigmf(float x) { return 1.f/(1.f + expf(-x)); }

// ---------------- prep: nv1T/nv2T [10][BNP] ----------------
__global__ __launch_bounds__(256) void prep_kernel(
    const float* __restrict__ tidE1, const float* __restrict__ tidE2,
    const float* __restrict__ diwE1, const float* __restrict__ diwE2,
    const float* __restrict__ nodeE,
    const int* __restrict__ tididx, const int* __restrict__ diwidx,
    int t, int tlen,
    float* __restrict__ nv1T, float* __restrict__ nv2T)
{
  int i = blockIdx.x*256 + threadIdx.x;
  if (i >= BN) return;
  int b = i / NN, n = i - b*NN;
  int gi = (b*tlen + t)*NN + n;
  int ti = tididx[gi]*DD, di = diwidx[gi]*DD;
  int nE = n*DD;
#pragma unroll
  for (int d = 0; d < DD; ++d) {
    float E = nodeE[nE+d];
    nv1T[d*BNP+i] = tanhf(E * (tidE1[ti+d] * diwE1[di+d]));
    nv2T[d*BNP+i] = tanhf(E * (tidE2[ti+d] * diwE2[di+d]));
  }
}

// ------- attn partial: exp(relu(nv1 nv2^T)) @ [x | h] over m-chunk, raw + rowsum -------
// grid (14, 32, 2). axP [2][65][BNP], ls [2][BNP]. No normalization here.
__global__ __launch_bounds__(256,4) void attn_kernel(
    const float* __restrict__ nv1T, const float* __restrict__ nv2T,
    const float* __restrict__ xsrc, int xmode, int t, int tlen,
    const float* __restrict__ hsrc,
    float* __restrict__ axP, float* __restrict__ ls)
{
  __shared__ float nv1s[DD][64];
  __shared__ float nv2s[DD][64];
  __shared__ float xt[64][68];    // col-swizzled: c<64 at c ^ ((m&7)<<3); col 64 at 64
  __shared__ float ps[64][68];
  int b = blockIdx.y;
  int mc = blockIdx.z;
  int r0 = blockIdx.x * 64;
  int tid = threadIdx.x;
  int rg = tid >> 4, cg = tid & 15;
  int base = b*NN;

  for (int idx = tid; idx < DD*64; idx += 256) {
    int d = idx >> 6, r = idx & 63;
    nv1s[d][r] = (r0 + r < NN) ? nv1T[d*BNP + base + r0 + r] : 0.f;
  }

  float acc[4][4] = {};
  float acc5p[4] = {};
  float acclp[4] = {};
  float xreg[17];
  float nvreg[3];

  int mstart = mc*448;
  int mend = min(NN, (mc+1)*448);

  // issue first tile's staging loads
  {
    int m0 = mstart;
#pragma unroll
    for (int j = 0; j < 17; ++j) {
      int idx = tid + j*256;
      if (idx < 4160) {
        int c = idx >> 6, m = idx & 63, mm = m0 + m;
        float v = 0.f;
        if (mm < NN) {
          if (c == 0) v = (xmode == 0) ? xsrc[(b*tlen+t)*NN + mm] : xsrc[base + mm];
          else        v = hsrc[(c-1)*BNP + base + mm];
        }
        xreg[j] = v;
      }
    }
#pragma unroll
    for (int j = 0; j < 3; ++j) {
      int idx = tid + j*256;
      if (idx < 640) {
        int d = idx >> 6, m = idx & 63, mm = m0 + m;
        nvreg[j] = (mm < NN) ? nv2T[d*BNP + base + mm] : 0.f;
      }
    }
  }

  for (int m0 = mstart; m0 < mend; m0 += 64) {
    int mv = min(64, NN - m0);
    __syncthreads();
    // store prefetched tile
#pragma unroll
    for (int j = 0; j < 17; ++j) {
      int idx = tid + j*256;
      if (idx < 4160) {
        int c = idx >> 6, m = idx & 63;
        int sc = (c < 64) ? (c ^ ((m & 7) << 3)) : 64;
        xt[m][sc] = xreg[j];
      }
    }
#pragma unroll
    for (int j = 0; j < 3; ++j) {
      int idx = tid + j*256;
      if (idx < 640) nv2s[idx >> 6][idx & 63] = nvreg[j];
    }
    __syncthreads();
    // issue next tile's loads
    if (m0 + 64 < mend) {
      int mn = m0 + 64;
#pragma unroll
      for (int j = 0; j < 17; ++j) {
        int idx = tid + j*256;
        if (idx < 4160) {
          int c = idx >> 6, m = idx & 63, mm = mn + m;
          float v = 0.f;
          if (mm < NN) {
            if (c == 0) v = (xmode == 0) ? xsrc[(b*tlen+t)*NN + mm] : xsrc[base + mm];
            else        v = hsrc[(c-1)*BNP + base + mm];
          }
          xreg[j] = v;
        }
      }
#pragma unroll
      for (int j = 0; j < 3; ++j) {
        int idx = tid + j*256;
        if (idx < 640) {
          int d = idx >> 6, m = idx & 63, mm = mn + m;
          nvreg[j] = (mm < NN) ? nv2T[d*BNP + base + mm] : 0.f;
        }
      }
    }
    // QK^T
    float s[4][4] = {};
#pragma unroll
    for (int d = 0; d < DD; ++d) {
      float4 a4 = *(const float4*)&nv1s[d][rg*4];
      float4 c4 = *(const float4*)&nv2s[d][cg*4];
      const float* ap = (const float*)&a4;
      const float* cp = (const float*)&c4;
#pragma unroll
      for (int j = 0; j < 4; ++j)
#pragma unroll
        for (int jj = 0; jj < 4; ++jj)
          s[j][jj] += ap[j]*cp[jj];
    }
    // exp + fold row-sums and x-column here (not in AV loop)
#pragma unroll
    for (int jj = 0; jj < 4; ++jj) {
      int m = cg*4 + jj;
      float xm = xt[m][64];
      float4 pv;
      float* pp = (float*)&pv;
#pragma unroll
      for (int j = 0; j < 4; ++j) {
        float e = (m < mv) ? expf(fmaxf(s[j][jj], 0.f)) : 0.f;
        pp[j] = e;
        acclp[j] += e;
        acc5p[j] = fmaf(e, xm, acc5p[j]);
      }
      *(float4*)&ps[m][rg*4] = pv;
    }
    __syncthreads();
    // AV: pure 16-FMA inner loop
#pragma unroll 4
    for (int m = 0; m < mv; ++m) {
      float4 p4 = *(const float4*)&ps[m][rg*4];
      float4 x4 = *(const float4*)&xt[m][(cg*4) ^ ((m & 7) << 3)];
      const float* pp = (const float*)&p4;
      const float* xp = (const float*)&x4;
#pragma unroll
      for (int j = 0; j < 4; ++j)
#pragma unroll
        for (int jj = 0; jj < 4; ++jj)
          acc[j][jj] += pp[j]*xp[jj];
    }
  }
  // reduce accl/acc5 over cg (lane bits 0..3)
#pragma unroll
  for (int off = 1; off <= 8; off <<= 1) {
#pragma unroll
    for (int j = 0; j < 4; ++j) {
      acclp[j] += __shfl_xor(acclp[j], off, 64);
      acc5p[j] += __shfl_xor(acc5p[j], off, 64);
    }
  }
  float* axPp = axP + (size_t)mc*65*BNP;
  float* lsp  = ls + (size_t)mc*BNP;
#pragma unroll
  for (int j = 0; j < 4; ++j) {
    int r = r0 + rg*4 + j;
    if (r < NN) {
#pragma unroll
      for (int jj = 0; jj < 4; ++jj)
        axPp[(cg*4+jj)*BNP + base + r] = acc[j][jj];
      if (cg == 0) {
        axPp[64*BNP + base + r] = acc5p[j];
        lsp[base + r] = acclp[j];
      }
    }
  }
}

// xgs rows: 0 = x, 1..64 = h(or zh), 65..129 = raw attn rows (A@[x,h] unnormalized)
// W rows:   0 = x, 1..64 = h,         65..129 = A-part, 130 = bias
// out = sum_d nv_d*(t1 + bias) + nv_d*lsi*t2

// ------- gate: grid (883, 2). M32 x N64. zr = sigmoid(pdg2). W software-pipelined -------
__global__ __launch_bounds__(256,3) void gate_kernel(
    const float* __restrict__ xsrc, int xmode, int t, int tlen,
    const float* __restrict__ h,
    const float* __restrict__ axP, const float* __restrict__ ls,
    const float* __restrict__ nv1T,
    const float* __restrict__ W, const float* __restrict__ bias,
    float* __restrict__ zh, float* __restrict__ rbuf)
{
  __shared__ float xgs[130][36];
  __shared__ float Ws[131][64];
  __shared__ float nvs[DD][32];
  __shared__ float lsi[32];
  int n0 = blockIdx.x*32;
  int co0 = blockIdx.y*64;
  int tid = threadIdx.x;
  int og = tid & 31, mg = tid >> 5;
  int m4 = mg*4, og2 = og*2;

  if (tid < 32) {
    int m = n0 + tid;
    lsi[tid] = 1.f/(ls[m] + ls[BNP+m]);
    float x;
    if (xmode == 0) { int b = m/NN; x = xsrc[(b*tlen+t)*NN + (m - b*NN)]; }
    else x = xsrc[m];
    xgs[0][tid] = x;
  }
  for (int idx = tid; idx < 64*8; idx += 256) {
    int j = idx >> 3, q = (idx & 7)*4;
    *(float4*)&xgs[1+j][q] = *(const float4*)&h[j*BNP + n0 + q];
  }
  for (int idx = tid; idx < 65*8; idx += 256) {
    int j = idx >> 3, q = (idx & 7)*4;
    float4 a0 = *(const float4*)&axP[j*BNP + n0 + q];
    float4 a1 = *(const float4*)&axP[(size_t)(65+j)*BNP + n0 + q];
    a0.x += a1.x; a0.y += a1.y; a0.z += a1.z; a0.w += a1.w;
    *(float4*)&xgs[65+j][q] = a0;
  }
  for (int idx = tid; idx < DD*8; idx += 256) {
    int dd = idx >> 3, q = (idx & 7)*4;
    *(float4*)&nvs[dd][q] = *(const float4*)&nv1T[dd*BNP + n0 + q];
  }

  float4 wreg[8];
  float wrem;
  int rki = 128 + (tid >> 6), ro = tid & 63;
  // issue W loads for d=0
  {
    const float* wb = W + (size_t)co0;
#pragma unroll
    for (int j = 0; j < 8; ++j) {
      int q = tid + j*256;
      wreg[j] = *(const float4*)&wb[(q>>4)*128 + ((q&15)<<2)];
    }
    if (tid < 192) wrem = (rki < 130) ? wb[rki*128 + ro] : bias[co0 + ro];
  }

  float acc[4][2] = {};
  for (int d = 0; d < DD; ++d) {
    __syncthreads();
#pragma unroll
    for (int j = 0; j < 8; ++j) {
      int q = tid + j*256;
      *(float4*)&Ws[q>>4][(q&15)<<2] = wreg[j];
    }
    if (tid < 192) Ws[rki][ro] = wrem;
    __syncthreads();
    if (d < DD-1) {
      const float* wb = W + (size_t)(d+1)*130*128 + co0;
#pragma unroll
      for (int j = 0; j < 8; ++j) {
        int q = tid + j*256;
        wreg[j] = *(const float4*)&wb[(q>>4)*128 + ((q&15)<<2)];
      }
      if (tid < 192) wrem = (rki < 130) ? wb[rki*128 + ro] : bias[(d+1)*128 + co0 + ro];
    }
    float t1[4][2] = {}, t2[4][2] = {};
#pragma unroll 5
    for (int ki = 0; ki < 65; ++ki) {
      float4 p4 = *(const float4*)&xgs[ki][m4];
      float2 w2 = *(const float2*)&Ws[ki][og2];
      const float* pv = (const float*)&p4;
#pragma unroll
      for (int r = 0; r < 4; ++r) {
        t1[r][0] = fmaf(pv[r], w2.x, t1[r][0]);
        t1[r][1] = fmaf(pv[r], w2.y, t1[r][1]);
      }
    }
#pragma unroll 5
    for (int ki = 0; ki < 65; ++ki) {
      float4 p4 = *(const float4*)&xgs[65+ki][m4];
      float2 w2 = *(const float2*)&Ws[65+ki][og2];
      const float* pv = (const float*)&p4;
#pragma unroll
      for (int r = 0; r < 4; ++r) {
        t2[r][0] = fmaf(pv[r], w2.x, t2[r][0]);
        t2[r][1] = fmaf(pv[r], w2.y, t2[r][1]);
      }
    }
    float2 bw = *(const float2*)&Ws[130][og2];
#pragma unroll
    for (int r = 0; r < 4; ++r) {
      float nv = nvs[d][m4+r];
      float nvl = nv * lsi[m4+r];
      acc[r][0] += nv*(t1[r][0]+bw.x) + nvl*t2[r][0];
      acc[r][1] += nv*(t1[r][1]+bw.y) + nvl*t2[r][1];
    }
  }

  int nb = n0 + m4;
  if (co0 == 0) {
#pragma unroll
    for (int c = 0; c < 2; ++c) {
      int o = og2 + c;
      float4 h4 = *(const float4*)&h[o*BNP + nb];
      float4 v;
      v.x = sigmf(acc[0][c])*h4.x;
      v.y = sigmf(acc[1][c])*h4.y;
      v.z = sigmf(acc[2][c])*h4.z;
      v.w = sigmf(acc[3][c])*h4.w;
      *(float4*)&zh[o*BNP + nb] = v;
    }
  } else {
#pragma unroll
    for (int c = 0; c < 2; ++c) {
      int o = og2 + c;
      float4 v;
      v.x = sigmf(acc[0][c]); v.y = sigmf(acc[1][c]);
      v.z = sigmf(acc[2][c]); v.w = sigmf(acc[3][c]);
      *(float4*)&rbuf[o*BNP + nb] = v;
    }
  }
}

// ------- upd: grid (883). M32 x N64. h = r*h + (1-r)*tanh(pdg2); dec: fused proj -------
__global__ __launch_bounds__(256,3) void upd_kernel(
    const float* __restrict__ xsrc, int xmode, int t, int tlen,
    const float* __restrict__ zh,
    const float* __restrict__ axP, const float* __restrict__ ls,
    const float* __restrict__ nv1T,
    const float* __restrict__ W, const float* __restrict__ bias,
    const float* __restrict__ rbuf, float* __restrict__ h,
    int dec, const float* __restrict__ pW, const float* __restrict__ pb,
    float* __restrict__ go, float* __restrict__ dout)
{
  __shared__ float xgs[130][36];
  __shared__ float Ws[131][64];
  __shared__ float nvs[DD][32];
  __shared__ float lsi[32];
  int n0 = blockIdx.x*32;
  int tid = threadIdx.x;
  int og = tid & 31, mg = tid >> 5;
  int m4 = mg*4, og2 = og*2;

  if (tid < 32) {
    int m = n0 + tid;
    lsi[tid] = 1.f/(ls[m] + ls[BNP+m]);
    float x;
    if (xmode == 0) { int b = m/NN; x = xsrc[(b*tlen+t)*NN + (m - b*NN)]; }
    else x = xsrc[m];
    xgs[0][tid] = x;
  }
  for (int idx = tid; idx < 64*8; idx += 256) {
    int j = idx >> 3, q = (idx & 7)*4;
    *(float4*)&xgs[1+j][q] = *(const float4*)&zh[j*BNP + n0 + q];
  }
  for (int idx = tid; idx < 65*8; idx += 256) {
    int j = idx >> 3, q = (idx & 7)*4;
    float4 a0 = *(const float4*)&axP[j*BNP + n0 + q];
    float4 a1 = *(const float4*)&axP[(size_t)(65+j)*BNP + n0 + q];
    a0.x += a1.x; a0.y += a1.y; a0.z += a1.z; a0.w += a1.w;
    *(float4*)&xgs[65+j][q] = a0;
  }
  for (int idx = tid; idx < DD*8; idx += 256) {
    int dd = idx >> 3, q = (idx & 7)*4;
    *(float4*)&nvs[dd][q] = *(const float4*)&nv1T[dd*BNP + n0 + q];
  }

  float4 wreg[8];
  float wrem;
  int rki = 128 + (tid >> 6), ro = tid & 63;
  {
    const float* wb = W;
#pragma unroll
    for (int j = 0; j < 8; ++j) {
      int q = tid + j*256;
      wreg[j] = *(const float4*)&wb[(q>>4)*64 + ((q&15)<<2)];
    }
    if (tid < 192) wrem = (rki < 130) ? wb[rki*64 + ro] : bias[ro];
  }

  float acc[4][2] = {};
  for (int d = 0; d < DD; ++d) {
    __syncthreads();
#pragma unroll
    for (int j = 0; j < 8; ++j) {
      int q = tid + j*256;
      *(float4*)&Ws[q>>4][(q&15)<<2] = wreg[j];
    }
    if (tid < 192) Ws[rki][ro] = wrem;
    __syncthreads();
    if (d < DD-1) {
      const float* wb = W + (size_t)(d+1)*130*64;
#pragma unroll
      for (int j = 0; j < 8; ++j) {
        int q = tid + j*256;
        wreg[j] = *(const float4*)&wb[(q>>4)*64 + ((q&15)<<2)];
      }
      if (tid < 192) wrem = (rki < 130) ? wb[rki*64 + ro] : bias[(d+1)*64 + ro];
    }
    float t1[4][2] = {}, t2[4][2] = {};
#pragma unroll 5
    for (int ki = 0; ki < 65; ++ki) {
      float4 p4 = *(const float4*)&xgs[ki][m4];
      float2 w2 = *(const float2*)&Ws[ki][og2];
      const float* pv = (const float*)&p4;
#pragma unroll
      for (int r = 0; r < 4; ++r) {
        t1[r][0] = fmaf(pv[r], w2.x, t1[r][0]);
        t1[r][1] = fmaf(pv[r], w2.y, t1[r][1]);
      }
    }
#pragma unroll 5
    for (int ki = 0; ki < 65; ++ki) {
      float4 p4 = *(const float4*)&xgs[65+ki][m4];
      float2 w2 = *(const float2*)&Ws[65+ki][og2];
      const float* pv = (const float*)&p4;
#pragma unroll
      for (int r = 0; r < 4; ++r) {
        t2[r][0] = fmaf(pv[r], w2.x, t2[r][0]);
        t2[r][1] = fmaf(pv[r], w2.y, t2[r][1]);
      }
    }
    float2 bw = *(const float2*)&Ws[130][og2];
#pragma unroll
    for (int r = 0; r < 4; ++r) {
      float nv = nvs[d][m4+r];
      float nvl = nv * lsi[m4+r];
      acc[r][0] += nv*(t1[r][0]+bw.x) + nvl*t2[r][0];
      acc[r][1] += nv*(t1[r][1]+bw.y) + nvl*t2[r][1];
    }
  }

  int nb = n0 + m4;
  float hn[4][2];
#pragma unroll
  for (int c = 0; c < 2; ++c) {
    int o = og2 + c;
    float4 r4 = *(const float4*)&rbuf[o*BNP + nb];
    float4 h4 = *(const float4*)&h[o*BNP + nb];
    hn[0][c] = r4.x*h4.x + (1.f-r4.x)*tanhf(acc[0][c]);
    hn[1][c] = r4.y*h4.y + (1.f-r4.y)*tanhf(acc[1][c]);
    hn[2][c] = r4.z*h4.z + (1.f-r4.z)*tanhf(acc[2][c]);
    hn[3][c] = r4.w*h4.w + (1.f-r4.w)*tanhf(acc[3][c]);
    float4 v = make_float4(hn[0][c], hn[1][c], hn[2][c], hn[3][c]);
    *(float4*)&h[o*BNP + nb] = v;
  }
  if (dec) {
    float* ppsum = &xgs[0][0];   // reuse as [32][33]
    float pw0 = pW[og2], pw1 = pW[og2+1];
    __syncthreads();
#pragma unroll
    for (int r = 0; r < 4; ++r)
      ppsum[(m4+r)*33 + og] = hn[r][0]*pw0 + hn[r][1]*pw1;
    __syncthreads();
    if (tid < 32) {
      float s = pb[0];
#pragma unroll 8
      for (int j = 0; j < 32; ++j) s += ppsum[tid*33 + j];
      int m = n0 + tid;
      go[m] = s;
      int b = m/NN, n = m - b*NN;
      dout[(b*HORZ + t)*NN + n] = s;
    }
  }
}

extern "C" void kernel_launch(void* const* d_in, const int* in_sizes, int n_in,
                              void* d_out, int out_size, void* d_ws, size_t ws_size,
                              hipStream_t stream) {
  (void)in_sizes; (void)n_in; (void)out_size; (void)ws_size;
  const float* src_vals = (const float*)d_in[0];
  const float* node_emb = (const float*)d_in[1];
  const float* tid1 = (const float*)d_in[2];
  const float* tid2 = (const float*)d_in[3];
  const float* diw1 = (const float*)d_in[4];
  const float* diw2 = (const float*)d_in[5];
  const float* egW = (const float*)d_in[6];
  const float* egb = (const float*)d_in[7];
  const float* euW = (const float*)d_in[8];
  const float* eub = (const float*)d_in[9];
  const float* dgW = (const float*)d_in[10];
  const float* dgb = (const float*)d_in[11];
  const float* duW = (const float*)d_in[12];
  const float* dub = (const float*)d_in[13];
  const float* pW  = (const float*)d_in[14];
  const float* pb  = (const float*)d_in[15];
  const int* stid = (const int*)d_in[16];
  const int* sdiw = (const int*)d_in[17];
  const int* ttid = (const int*)d_in[18];
  const int* tdiw = (const int*)d_in[19];
  float* out = (float*)d_out;

  float* wp = (float*)d_ws;
  float* hbuf = wp; wp += (size_t)64*BNP;
  float* zh   = wp; wp += (size_t)64*BNP;
  float* rbuf = wp; wp += (size_t)64*BNP;
  float* axP  = wp; wp += (size_t)2*65*BNP;
  float* ls   = wp; wp += (size_t)2*BNP;
  float* nv1T = wp; wp += (size_t)DD*BNP;
  float* nv2T = wp; wp += (size_t)DD*BNP;
  float* go   = wp; wp += BN;

  hipMemsetAsync(hbuf, 0, sizeof(float)*(size_t)64*BNP, stream);
  hipMemsetAsync(go, 0, sizeof(float)*BN, stream);

  dim3 agrid(14, BB, 2);
  dim3 ggrid(883, 2);
  for (int t = 0; t < TSRC; ++t) {
    prep_kernel<<<111,256,0,stream>>>(tid1,tid2,diw1,diw2,node_emb,stid,sdiw,t,TSRC,nv1T,nv2T);
    attn_kernel<<<agrid,256,0,stream>>>(nv1T,nv2T,src_vals,0,t,TSRC,hbuf,axP,ls);
    gate_kernel<<<ggrid,256,0,stream>>>(src_vals,0,t,TSRC,hbuf,axP,ls,nv1T,egW,egb,zh,rbuf);
    attn_kernel<<<agrid,256,0,stream>>>(nv1T,nv2T,src_vals,0,t,TSRC,zh,axP,ls);
    upd_kernel<<<883,256,0,stream>>>(src_vals,0,t,TSRC,zh,axP,ls,nv1T,euW,eub,rbuf,hbuf,0,pW,pb,go,out);
  }
  for (int t = 0; t < HORZ; ++t) {
    prep_kernel<<<111,256,0,stream>>>(tid1,tid2,diw1,diw2,node_emb,ttid,tdiw,t,HORZ,nv1T,nv2T);
    attn_kernel<<<agrid,256,0,stream>>>(nv1T,nv2T,go,1,t,HORZ,hbuf,axP,ls);
    gate_kernel<<<ggrid,256,0,stream>>>(go,1,t,HORZ,hbuf,axP,ls,nv1T,dgW,dgb,zh,rbuf);
    attn_kernel<<<agrid,256,0,stream>>>(nv1T,nv2T,go,1,t,HORZ,zh,axP,ls);
    upd_kernel<<<883,256,0,stream>>>(go,1,t,HORZ,zh,axP,ls,nv1T,duW,dub,rbuf,hbuf,1,pW,pb,go,out);
  }
}

// Round 7
// 11092.970 us; speedup vs baseline: 1.4420x; 1.4420x over previous
//
#include <hip/hip_runtime.h>

#define BB 32
#define TSRC 12
#define HORZ 12
#define NN 883
#define DD 10
#define HH 64
#define BN (BB*NN)     // 28256
#define BNP 28288      // 64-aligned stride

static __device__ __forceinline__ float sigmf(float x) { return 1.f/(1.f + __expf(-x)); }
static __device__ __forceinline__ float tanh_fast(float x) {
  float e = __expf(2.f*x);
  return (e - 1.f) / (e + 1.f);
}

// ---------------- prep: nv1T/nv2T [10][BNP] ----------------
__global__ __launch_bounds__(256) void prep_kernel(
    const float* __restrict__ tidE1, const float* __restrict__ tidE2,
    const float* __restrict__ diwE1, const float* __restrict__ diwE2,
    const float* __restrict__ nodeE,
    const int* __restrict__ tididx, const int* __restrict__ diwidx,
    int t, int tlen,
    float* __restrict__ nv1T, float* __restrict__ nv2T)
{
  int i = blockIdx.x*256 + threadIdx.x;
  if (i >= BN) return;
  int b = i / NN, n = i - b*NN;
  int gi = (b*tlen + t)*NN + n;
  int ti = tididx[gi]*DD, di = diwidx[gi]*DD;
  int nE = n*DD;
#pragma unroll
  for (int d = 0; d < DD; ++d) {
    float E = nodeE[nE+d];
    nv1T[d*BNP+i] = tanh_fast(E * (tidE1[ti+d] * diwE1[di+d]));
    nv2T[d*BNP+i] = tanh_fast(E * (tidE2[ti+d] * diwE2[di+d]));
  }
}

// ------- attn partial: exp(relu(nv1 nv2^T)) @ [x | h] over m-chunk, raw + rowsum -------
// grid (14, 32, 2). axP [2][65][BNP], ls [2][BNP]. No normalization here.
__global__ __launch_bounds__(256,3) void attn_kernel(
    const float* __restrict__ nv1T, const float* __restrict__ nv2T,
    const float* __restrict__ xsrc, int xmode, int t, int tlen,
    const float* __restrict__ hsrc,
    float* __restrict__ axP, float* __restrict__ ls)
{
  __shared__ float nv1s[DD][64];
  __shared__ float nv2s[DD][64];
  __shared__ float xt[64][68];    // col-swizzled: c<64 at c ^ ((m&7)<<3); col 64 at 64
  __shared__ float ps[64][68];
  int b = blockIdx.y;
  int mc = blockIdx.z;
  int r0 = blockIdx.x * 64;
  int tid = threadIdx.x;
  int rg = tid >> 4, cg = tid & 15;
  int base = b*NN;

  for (int idx = tid; idx < DD*64; idx += 256) {
    int d = idx >> 6, r = idx & 63;
    nv1s[d][r] = (r0 + r < NN) ? nv1T[d*BNP + base + r0 + r] : 0.f;
  }

  float acc[4][4] = {};
  float acc5p[4] = {};
  float acclp[4] = {};

  int mstart = mc*448;
  int mend = min(NN, (mc+1)*448);

  for (int m0 = mstart; m0 < mend; m0 += 64) {
    int mv = min(64, NN - m0);
    __syncthreads();
    for (int idx = tid; idx < DD*64; idx += 256) {
      int d = idx >> 6, m = idx & 63;
      nv2s[d][m] = (m0 + m < NN) ? nv2T[d*BNP + base + m0 + m] : 0.f;
    }
    for (int j = 0; j < 17; ++j) {
      int idx = tid + j*256;
      if (idx < 4160) {
        int c = idx >> 6, m = idx & 63, mm = m0 + m;
        float v = 0.f;
        if (mm < NN) {
          if (c == 0) v = (xmode == 0) ? xsrc[(b*tlen+t)*NN + mm] : xsrc[base + mm];
          else        v = hsrc[(c-1)*BNP + base + mm];
        }
        int sc = (c < 64) ? (c ^ ((m & 7) << 3)) : 64;
        xt[m][sc] = v;
      }
    }
    __syncthreads();
    // QK^T
    float s[4][4] = {};
#pragma unroll
    for (int d = 0; d < DD; ++d) {
      float4 a4 = *(const float4*)&nv1s[d][rg*4];
      float4 c4 = *(const float4*)&nv2s[d][cg*4];
      const float* ap = (const float*)&a4;
      const float* cp = (const float*)&c4;
#pragma unroll
      for (int j = 0; j < 4; ++j)
#pragma unroll
        for (int jj = 0; jj < 4; ++jj)
          s[j][jj] += ap[j]*cp[jj];
    }
    // exp + fold row-sums and x-column; rows m>=mv zeroed so AV needs no guards
#pragma unroll
    for (int jj = 0; jj < 4; ++jj) {
      int m = cg*4 + jj;
      float xm = xt[m][64];
      float4 pv;
      float* pp = (float*)&pv;
#pragma unroll
      for (int j = 0; j < 4; ++j) {
        float e = (m < mv) ? __expf(fmaxf(s[j][jj], 0.f)) : 0.f;
        pp[j] = e;
        acclp[j] += e;
        acc5p[j] = fmaf(e, xm, acc5p[j]);
      }
      *(float4*)&ps[m][rg*4] = pv;
    }
    __syncthreads();
    // AV: uniform 64-deep, 4-unrolled, immediate offsets
    int xorc = cg*4;
    const float* psb = &ps[0][rg*4];
#pragma unroll 4
    for (int m8 = 0; m8 < 64; m8 += 4) {
      float4 p[4], x[4];
#pragma unroll
      for (int u = 0; u < 4; ++u) {
        p[u] = *(const float4*)(psb + (m8+u)*68);
        x[u] = *(const float4*)&xt[m8+u][xorc ^ (((m8+u) & 7) << 3)];
      }
#pragma unroll
      for (int u = 0; u < 4; ++u) {
        const float* pp = (const float*)&p[u];
        const float* xp = (const float*)&x[u];
#pragma unroll
        for (int j = 0; j < 4; ++j)
#pragma unroll
          for (int jj = 0; jj < 4; ++jj)
            acc[j][jj] += pp[j]*xp[jj];
      }
    }
  }
  // reduce accl/acc5 over cg (lane bits 0..3)
#pragma unroll
  for (int off = 1; off <= 8; off <<= 1) {
#pragma unroll
    for (int j = 0; j < 4; ++j) {
      acclp[j] += __shfl_xor(acclp[j], off, 64);
      acc5p[j] += __shfl_xor(acc5p[j], off, 64);
    }
  }
  float* axPp = axP + (size_t)mc*65*BNP;
  float* lsp  = ls + (size_t)mc*BNP;
#pragma unroll
  for (int j = 0; j < 4; ++j) {
    int r = r0 + rg*4 + j;
    if (r < NN) {
#pragma unroll
      for (int jj = 0; jj < 4; ++jj)
        axPp[(cg*4+jj)*BNP + base + r] = acc[j][jj];
      if (cg == 0) {
        axPp[64*BNP + base + r] = acc5p[j];
        lsp[base + r] = acclp[j];
      }
    }
  }
}

// xgs rows: 0 = x, 1..64 = h(or zh), 65..129 = raw attn rows (unnormalized)
// W rows:   0 = x, 1..64 = h,         65..129 = A-part, 130 = bias
// out = sum_d nv_d*(t1 + bias) + nv_d*lsi*t2

// ------- gate: grid (442, 2). M64 x N64, 4x4/thread. zr = sigmoid(pdg2) -------
__global__ __launch_bounds__(256,2) void gate_kernel(
    const float* __restrict__ xsrc, int xmode, int t, int tlen,
    const float* __restrict__ h,
    const float* __restrict__ axP, const float* __restrict__ ls,
    const float* __restrict__ nv1T,
    const float* __restrict__ W, const float* __restrict__ bias,
    float* __restrict__ zh, float* __restrict__ rbuf)
{
  __shared__ float xgs[130][68];
  __shared__ float Ws[131][64];
  __shared__ float nvs[DD][64];
  __shared__ float lsi[64];
  int n0 = blockIdx.x*64;
  int co0 = blockIdx.y*64;
  int tid = threadIdx.x;
  int mg = tid & 15, og = tid >> 4;
  int m4 = mg*4, og4 = og*4;

  if (tid < 64) {
    int m = n0 + tid;
    lsi[tid] = 1.f/(ls[m] + ls[BNP+m]);
    float x = 0.f;
    if (m < BN) {
      if (xmode == 0) { int b = m/NN; x = xsrc[(b*tlen+t)*NN + (m - b*NN)]; }
      else x = xsrc[m];
    }
    xgs[0][tid] = x;
  }
  for (int idx = tid; idx < 64*16; idx += 256) {
    int j = idx >> 4, q = (idx & 15)*4;
    *(float4*)&xgs[1+j][q] = *(const float4*)&h[j*BNP + n0 + q];
  }
  for (int idx = tid; idx < 65*16; idx += 256) {
    int j = idx >> 4, q = (idx & 15)*4;
    float4 a0 = *(const float4*)&axP[(size_t)j*BNP + n0 + q];
    float4 a1 = *(const float4*)&axP[(size_t)(65+j)*BNP + n0 + q];
    a0.x += a1.x; a0.y += a1.y; a0.z += a1.z; a0.w += a1.w;
    *(float4*)&xgs[65+j][q] = a0;
  }
  for (int idx = tid; idx < DD*16; idx += 256) {
    int dd = idx >> 4, q = (idx & 15)*4;
    *(float4*)&nvs[dd][q] = *(const float4*)&nv1T[dd*BNP + n0 + q];
  }

  float acc[4][4] = {};
  for (int d = 0; d < DD; ++d) {
    __syncthreads();
    for (int j = 0; j < 9; ++j) {
      int idx = tid + j*256;
      if (idx < 2096) {
        int ki = idx >> 4, o4 = (idx & 15)*4;
        float4 wv;
        if (ki < 130) wv = *(const float4*)&W[(size_t)(d*130 + ki)*128 + co0 + o4];
        else          wv = *(const float4*)&bias[d*128 + co0 + o4];
        *(float4*)&Ws[ki][o4] = wv;
      }
    }
    __syncthreads();
    float t1[4][4] = {}, t2[4][4] = {};
    const float* xga = &xgs[0][m4];
    const float* xgb = &xgs[65][m4];
    const float* wsa = &Ws[0][og4];
    const float* wsb = &Ws[65][og4];
#pragma unroll 5
    for (int ki = 0; ki < 65; ++ki) {
      float4 pa = *(const float4*)(xga + ki*68);
      float4 wa = *(const float4*)(wsa + ki*64);
      float4 pb = *(const float4*)(xgb + ki*68);
      float4 wb = *(const float4*)(wsb + ki*64);
      const float* pav = (const float*)&pa;
      const float* wav = (const float*)&wa;
      const float* pbv = (const float*)&pb;
      const float* wbv = (const float*)&wb;
#pragma unroll
      for (int r = 0; r < 4; ++r)
#pragma unroll
        for (int c = 0; c < 4; ++c) {
          t1[r][c] = fmaf(pav[r], wav[c], t1[r][c]);
          t2[r][c] = fmaf(pbv[r], wbv[c], t2[r][c]);
        }
    }
    float4 bw = *(const float4*)&Ws[130][og4];
    const float* bwv = (const float*)&bw;
#pragma unroll
    for (int r = 0; r < 4; ++r) {
      float nv = nvs[d][m4+r];
      float nvl = nv * lsi[m4+r];
#pragma unroll
      for (int c = 0; c < 4; ++c)
        acc[r][c] += nv*(t1[r][c]+bwv[c]) + nvl*t2[r][c];
    }
  }

  int nb = n0 + m4;
  if (co0 == 0) {   // z half -> cand = z*h (h is in xgs rows 1..64)
#pragma unroll
    for (int c = 0; c < 4; ++c) {
      int o = og4 + c;
      float4 h4 = *(const float4*)&xgs[1+o][m4];
      float4 v;
      v.x = sigmf(acc[0][c])*h4.x;
      v.y = sigmf(acc[1][c])*h4.y;
      v.z = sigmf(acc[2][c])*h4.z;
      v.w = sigmf(acc[3][c])*h4.w;
      *(float4*)&zh[o*BNP + nb] = v;
    }
  } else {          // r half
#pragma unroll
    for (int c = 0; c < 4; ++c) {
      int o = og4 + c;
      float4 v;
      v.x = sigmf(acc[0][c]); v.y = sigmf(acc[1][c]);
      v.z = sigmf(acc[2][c]); v.w = sigmf(acc[3][c]);
      *(float4*)&rbuf[o*BNP + nb] = v;
    }
  }
}

// ------- upd: grid (442). M64 x N64, 4x4/thread. h = r*h + (1-r)*tanh(pdg2); dec: fused proj -------
__global__ __launch_bounds__(256,2) void upd_kernel(
    const float* __restrict__ xsrc, int xmode, int t, int tlen,
    const float* __restrict__ zh,
    const float* __restrict__ axP, const float* __restrict__ ls,
    const float* __restrict__ nv1T,
    const float* __restrict__ W, const float* __restrict__ bias,
    const float* __restrict__ rbuf, float* __restrict__ h,
    int dec, const float* __restrict__ pW, const float* __restrict__ pb,
    float* __restrict__ go, float* __restrict__ dout)
{
  __shared__ float xgs[130][68];
  __shared__ float Ws[131][64];
  __shared__ float nvs[DD][64];
  __shared__ float lsi[64];
  int n0 = blockIdx.x*64;
  int tid = threadIdx.x;
  int mg = tid & 15, og = tid >> 4;
  int m4 = mg*4, og4 = og*4;

  if (tid < 64) {
    int m = n0 + tid;
    lsi[tid] = 1.f/(ls[m] + ls[BNP+m]);
    float x = 0.f;
    if (m < BN) {
      if (xmode == 0) { int b = m/NN; x = xsrc[(b*tlen+t)*NN + (m - b*NN)]; }
      else x = xsrc[m];
    }
    xgs[0][tid] = x;
  }
  for (int idx = tid; idx < 64*16; idx += 256) {
    int j = idx >> 4, q = (idx & 15)*4;
    *(float4*)&xgs[1+j][q] = *(const float4*)&zh[j*BNP + n0 + q];
  }
  for (int idx = tid; idx < 65*16; idx += 256) {
    int j = idx >> 4, q = (idx & 15)*4;
    float4 a0 = *(const float4*)&axP[(size_t)j*BNP + n0 + q];
    float4 a1 = *(const float4*)&axP[(size_t)(65+j)*BNP + n0 + q];
    a0.x += a1.x; a0.y += a1.y; a0.z += a1.z; a0.w += a1.w;
    *(float4*)&xgs[65+j][q] = a0;
  }
  for (int idx = tid; idx < DD*16; idx += 256) {
    int dd = idx >> 4, q = (idx & 15)*4;
    *(float4*)&nvs[dd][q] = *(const float4*)&nv1T[dd*BNP + n0 + q];
  }

  float acc[4][4] = {};
  for (int d = 0; d < DD; ++d) {
    __syncthreads();
    for (int j = 0; j < 9; ++j) {
      int idx = tid + j*256;
      if (idx < 2096) {
        int ki = idx >> 4, o4 = (idx & 15)*4;
        float4 wv;
        if (ki < 130) wv = *(const float4*)&W[(size_t)(d*130 + ki)*64 + o4];
        else          wv = *(const float4*)&bias[d*64 + o4];
        *(float4*)&Ws[ki][o4] = wv;
      }
    }
    __syncthreads();
    float t1[4][4] = {}, t2[4][4] = {};
    const float* xga = &xgs[0][m4];
    const float* xgb = &xgs[65][m4];
    const float* wsa = &Ws[0][og4];
    const float* wsb = &Ws[65][og4];
#pragma unroll 5
    for (int ki = 0; ki < 65; ++ki) {
      float4 pa = *(const float4*)(xga + ki*68);
      float4 wa = *(const float4*)(wsa + ki*64);
      float4 pb = *(const float4*)(xgb + ki*68);
      float4 wb = *(const float4*)(wsb + ki*64);
      const float* pav = (const float*)&pa;
      const float* wav = (const float*)&wa;
      const float* pbv = (const float*)&pb;
      const float* wbv = (const float*)&wb;
#pragma unroll
      for (int r = 0; r < 4; ++r)
#pragma unroll
        for (int c = 0; c < 4; ++c) {
          t1[r][c] = fmaf(pav[r], wav[c], t1[r][c]);
          t2[r][c] = fmaf(pbv[r], wbv[c], t2[r][c]);
        }
    }
    float4 bw = *(const float4*)&Ws[130][og4];
    const float* bwv = (const float*)&bw;
#pragma unroll
    for (int r = 0; r < 4; ++r) {
      float nv = nvs[d][m4+r];
      float nvl = nv * lsi[m4+r];
#pragma unroll
      for (int c = 0; c < 4; ++c)
        acc[r][c] += nv*(t1[r][c]+bwv[c]) + nvl*t2[r][c];
    }
  }

  int nb = n0 + m4;
  float hn[4][4];
#pragma unroll
  for (int c = 0; c < 4; ++c) {
    int o = og4 + c;
    float4 r4 = *(const float4*)&rbuf[o*BNP + nb];
    float4 h4 = *(const float4*)&h[o*BNP + nb];
    hn[0][c] = r4.x*h4.x + (1.f-r4.x)*tanhf(acc[0][c]);
    hn[1][c] = r4.y*h4.y + (1.f-r4.y)*tanhf(acc[1][c]);
    hn[2][c] = r4.z*h4.z + (1.f-r4.z)*tanhf(acc[2][c]);
    hn[3][c] = r4.w*h4.w + (1.f-r4.w)*tanhf(acc[3][c]);
    float4 v = make_float4(hn[0][c], hn[1][c], hn[2][c], hn[3][c]);
    *(float4*)&h[o*BNP + nb] = v;
  }
  if (dec) {
    float* ppsum = &xgs[0][0];   // reuse as [64][17]
    __syncthreads();
#pragma unroll
    for (int r = 0; r < 4; ++r) {
      float s = 0.f;
#pragma unroll
      for (int c = 0; c < 4; ++c) s = fmaf(hn[r][c], pW[og4+c], s);
      ppsum[(m4+r)*17 + og] = s;
    }
    __syncthreads();
    if (tid < 64) {
      int m = n0 + tid;
      if (m < BN) {
        float s = pb[0];
#pragma unroll
        for (int j = 0; j < 16; ++j) s += ppsum[tid*17 + j];
        go[m] = s;
        int b = m/NN, n = m - b*NN;
        dout[(b*HORZ + t)*NN + n] = s;
      }
    }
  }
}

extern "C" void kernel_launch(void* const* d_in, const int* in_sizes, int n_in,
                              void* d_out, int out_size, void* d_ws, size_t ws_size,
                              hipStream_t stream) {
  (void)in_sizes; (void)n_in; (void)out_size; (void)ws_size;
  const float* src_vals = (const float*)d_in[0];
  const float* node_emb = (const float*)d_in[1];
  const float* tid1 = (const float*)d_in[2];
  const float* tid2 = (const float*)d_in[3];
  const float* diw1 = (const float*)d_in[4];
  const float* diw2 = (const float*)d_in[5];
  const float* egW = (const float*)d_in[6];
  const float* egb = (const float*)d_in[7];
  const float* euW = (const float*)d_in[8];
  const float* eub = (const float*)d_in[9];
  const float* dgW = (const float*)d_in[10];
  const float* dgb = (const float*)d_in[11];
  const float* duW = (const float*)d_in[12];
  const float* dub = (const float*)d_in[13];
  const float* pW  = (const float*)d_in[14];
  const float* pb  = (const float*)d_in[15];
  const int* stid = (const int*)d_in[16];
  const int* sdiw = (const int*)d_in[17];
  const int* ttid = (const int*)d_in[18];
  const int* tdiw = (const int*)d_in[19];
  float* out = (float*)d_out;

  float* wp = (float*)d_ws;
  float* hbuf = wp; wp += (size_t)64*BNP;
  float* zh   = wp; wp += (size_t)64*BNP;
  float* rbuf = wp; wp += (size_t)64*BNP;
  float* axP  = wp; wp += (size_t)2*65*BNP;
  float* ls   = wp; wp += (size_t)2*BNP;
  float* nv1T = wp; wp += (size_t)DD*BNP;
  float* nv2T = wp; wp += (size_t)DD*BNP;
  float* go   = wp; wp += BN;

  hipMemsetAsync(hbuf, 0, sizeof(float)*(size_t)64*BNP, stream);
  hipMemsetAsync(go, 0, sizeof(float)*BN, stream);

  dim3 agrid(14, BB, 2);
  dim3 ggrid(442, 2);
  for (int t = 0; t < TSRC; ++t) {
    prep_kernel<<<111,256,0,stream>>>(tid1,tid2,diw1,diw2,node_emb,stid,sdiw,t,TSRC,nv1T,nv2T);
    attn_kernel<<<agrid,256,0,stream>>>(nv1T,nv2T,src_vals,0,t,TSRC,hbuf,axP,ls);
    gate_kernel<<<ggrid,256,0,stream>>>(src_vals,0,t,TSRC,hbuf,axP,ls,nv1T,egW,egb,zh,rbuf);
    attn_kernel<<<agrid,256,0,stream>>>(nv1T,nv2T,src_vals,0,t,TSRC,zh,axP,ls);
    upd_kernel<<<442,256,0,stream>>>(src_vals,0,t,TSRC,zh,axP,ls,nv1T,euW,eub,rbuf,hbuf,0,pW,pb,go,out);
  }
  for (int t = 0; t < HORZ; ++t) {
    prep_kernel<<<111,256,0,stream>>>(tid1,tid2,diw1,diw2,node_emb,ttid,tdiw,t,HORZ,nv1T,nv2T);
    attn_kernel<<<agrid,256,0,stream>>>(nv1T,nv2T,go,1,t,HORZ,hbuf,axP,ls);
    gate_kernel<<<ggrid,256,0,stream>>>(go,1,t,HORZ,hbuf,axP,ls,nv1T,dgW,dgb,zh,rbuf);
    attn_kernel<<<agrid,256,0,stream>>>(nv1T,nv2T,go,1,t,HORZ,zh,axP,ls);
    upd_kernel<<<442,256,0,stream>>>(go,1,t,HORZ,zh,axP,ls,nv1T,duW,dub,rbuf,hbuf,1,pW,pb,go,out);
  }
}